// Round 9
// baseline (83.043 us; speedup 1.0000x reference)
//
#include <hip/hip_runtime.h>
#include <hip/hip_bf16.h>

#define S_LEN 2048
#define NH 16
#define HD 64

typedef __attribute__((ext_vector_type(8))) __bf16 bf16x8;
typedef __attribute__((ext_vector_type(16))) float f32x16;

// 0.125 (1/sqrt(64)) * log2(e): folded into Q so softmax uses exp2 directly
#define QSCALE 0.1803368801111204f

static __device__ __forceinline__ ushort f2bf(float f) {
    unsigned int u = __float_as_uint(f);
    u += 0x7fffu + ((u >> 16) & 1u);
    return (ushort)(u >> 16);
}

static __device__ __forceinline__ void gload16(const void* g, void* l) {
    __builtin_amdgcn_global_load_lds(
        (const __attribute__((address_space(1))) unsigned int*)g,
        (__attribute__((address_space(3))) unsigned int*)l, 16, 0, 0);
}

static __device__ __forceinline__ unsigned cvtpk_bf16(float lo, float hi) {
    unsigned r;
    asm("v_cvt_pk_bf16_f32 %0, %1, %2" : "=v"(r) : "v"(lo), "v"(hi));
    return r;
}
static __device__ __forceinline__ float exp2_fast(float x) {
    float r;
    asm("v_exp_f32 %0, %1" : "=v"(r) : "v"(x));
    return r;
}

// ---------------------------------------------------------------------------
// K prepass: [B,S,H,D] f32 -> frag-order bf16.  (r2/r7-proven, verbatim)
// ---------------------------------------------------------------------------
__global__ __launch_bounds__(256) void prep_k_kernel(const float* __restrict__ in,
                                                     ushort* __restrict__ out) {
    unsigned t = blockIdx.x * 256u + threadIdx.x;   // 524288 total
    unsigned o = t & 7u;            // d-octet
    unsigned s = (t >> 3) & 2047u;
    unsigned bh = t >> 14;
    unsigned b = bh >> 4, h = bh & 15u;
    const float* src = in + (((size_t)(b * S_LEN) + s) * NH + h) * HD + o * 8;
    float4 x = *(const float4*)src;
    float4 y = *(const float4*)(src + 4);
    union { ushort u[8]; uint4 q; } fu;
    fu.u[0] = f2bf(x.x); fu.u[1] = f2bf(x.y); fu.u[2] = f2bf(x.z); fu.u[3] = f2bf(x.w);
    fu.u[4] = f2bf(y.x); fu.u[5] = f2bf(y.y); fu.u[6] = f2bf(y.z); fu.u[7] = f2bf(y.w);
    unsigned kt = s >> 6, kh = (s >> 5) & 1u, kl = s & 31u;
    unsigned dchunk = o >> 1, ho = o & 1u;
    size_t ci = (((size_t)(bh * 32u + kt) * 2u + kh) * 4u + dchunk) * 64u + kl + 32u * ho;
    *(uint4*)(out + ci * 8u) = fu.q;
}

// ---------------------------------------------------------------------------
// V prepass: [B,S,H,D] f32 -> frag-order V^T bf16.  (r2/r7-proven, verbatim)
// ---------------------------------------------------------------------------
__global__ __launch_bounds__(256) void prep_v_kernel(const float* __restrict__ in,
                                                     ushort* __restrict__ out) {
    __shared__ float T[64][68];
    const unsigned tid = threadIdx.x;
    const unsigned kt = blockIdx.x, bh = blockIdx.y;
    const unsigned b = bh >> 4, h = bh & 15u;
#pragma unroll
    for (int i = 0; i < 4; ++i) {
        unsigned idx = tid + i * 256u;
        unsigned sl = idx >> 4, d4 = (idx & 15u) * 4u;
        float4 v = *(const float4*)(in + (((size_t)(b * S_LEN) + kt * 64u + sl) * NH + h) * HD + d4);
        *(float4*)&T[sl][d4] = v;
    }
    __syncthreads();
#pragma unroll
    for (int it = 0; it < 2; ++it) {
        unsigned ct = tid + it * 256u;
        unsigned l = ct & 63u, sub = ct >> 6;
        unsigned nt = sub & 1u, c = (sub >> 1) & 1u, kh = sub >> 2;
        unsigned d = (l & 31u) + 32u * nt;
        unsigned kb = kh * 32u + c * 16u + (l >> 5) * 8u;
        union { ushort u[8]; uint4 q; } fu;
#pragma unroll
        for (int j = 0; j < 8; ++j) fu.u[j] = f2bf(T[kb + j][d]);
        *(uint4*)(out + ((size_t)(bh * 32u + kt) * 8u + sub) * 512u + l * 8u) = fu.q;
    }
}

// ---------------------------------------------------------------------------
// Flash attention: 8 waves (4 q-subtiles x 2 key-groups), KV tile 64.
// r9: K triple-buffered in LDS (vmcnt(2)+s_barrier per tile, near-free wait);
// V + mask read DIRECT global->register from frag-order ws (L2-resident;
// compiler auto-waitcnt guards register loads); permlane32_swap P-pack
// (r3-algebra, exonerated by r7's C-init conviction); post-MFMA cndmask
// masking (C-init BANNED). LDS: K 48KB + combine overlay.
// ---------------------------------------------------------------------------
struct CombMem {
    float ob[4][32][64];    // 32 KB
    float lsb[4][64];
    float rls[4][32];
};
union SMemU {
    ushort K[2][3][4096];   // [kgrp][buf] 48 KB
    CombMem c;
};

__global__ __launch_bounds__(512, 4) void attn_kernel(const float* __restrict__ Qp,
                                                      const ushort* __restrict__ Kws,
                                                      const ushort* __restrict__ Vws,
                                                      const int* __restrict__ maskp,
                                                      float* __restrict__ outp) {
    __shared__ __align__(16) SMemU sm;

    const unsigned tid = threadIdx.x;
    const unsigned wid = tid >> 6;
    const unsigned lane = tid & 63u;
    const unsigned l31 = lane & 31u;
    const unsigned hi = lane >> 5;
    const unsigned qsub = wid & 3u;
    const unsigned kgrp = wid >> 2;

    const unsigned bh = blockIdx.y;
    const unsigned b = bh >> 4, h = bh & 15u;
    const unsigned q0 = blockIdx.x * 128u + qsub * 32u;

    // Q fragments (B-operand of swapped QK^T): lane holds Q[q0+l31][16dc+8hi+j]
    bf16x8 qf[4];
    {
        const float* qb = Qp + (((size_t)(b * S_LEN) + q0 + l31) * NH + h) * HD + hi * 8u;
#pragma unroll
        for (int dc = 0; dc < 4; ++dc) {
            float4 x = *(const float4*)(qb + dc * 16);
            float4 y = *(const float4*)(qb + dc * 16 + 4);
            union { ushort u[8]; bf16x8 v; } fu;
            fu.u[0] = f2bf(x.x * QSCALE); fu.u[1] = f2bf(x.y * QSCALE);
            fu.u[2] = f2bf(x.z * QSCALE); fu.u[3] = f2bf(x.w * QSCALE);
            fu.u[4] = f2bf(y.x * QSCALE); fu.u[5] = f2bf(y.y * QSCALE);
            fu.u[6] = f2bf(y.z * QSCALE); fu.u[7] = f2bf(y.w * QSCALE);
            qf[dc] = fu.v;
        }
    }

    f32x16 oacc0 = {0,0,0,0,0,0,0,0,0,0,0,0,0,0,0,0};
    f32x16 oacc1 = {0,0,0,0,0,0,0,0,0,0,0,0,0,0,0,0};
    float ls0 = 0.f, ls1 = 0.f, ls2 = 0.f, ls3 = 0.f;

    // K staging pointers (group kgrp covers tiles kgrp*16..+15)
    const char* kgp = (const char*)Kws + (size_t)bh * 262144u
                    + ((size_t)kgrp * 131072u) + (2u * qsub) * 1024u + lane * 16u;
    // V direct-read base (ushort units): bh stride 131072, kgrp 65536
    const ushort* vg = Vws + (size_t)bh * 131072u + (size_t)kgrp * 65536u + lane * 8u;
    // mask direct-read base
    const int* mg = maskp + (size_t)b * S_LEN + kgrp * 1024u;

    ushort* klb = &sm.K[kgrp][0][2u * qsub * 512u];
    const ushort* krd = &sm.K[kgrp][0][0];

#define STAGE(I, PB) do {                                                      \
    const size_t toff = (size_t)(I) * 8192u;                                   \
    gload16(kgp + toff,         klb + (PB) * 4096u);                           \
    gload16(kgp + toff + 1024u, klb + (PB) * 4096u + 512u);                    \
  } while (0)

    // prologue: stage K tiles 0,1 into bufs 0,1; wait tile 0 (FIFO: vmcnt(2)
    // retires the oldest 2 = tile 0's ops)
    STAGE(0, 0u);
    STAGE(1, 1u);
    asm volatile("s_waitcnt vmcnt(2)" ::: "memory");
    __builtin_amdgcn_s_barrier();

    unsigned cur = 0u;
    for (int i = 0; i < 16; ++i) {
        if (i < 14) {
            unsigned pb = (cur == 2u) ? 1u : ((cur == 1u) ? 0u : 2u);  // (cur+2)%3
            STAGE(i + 2, pb);
        }
        const ushort* kr = krd + cur * 4096u;
        const ushort* vt = vg + (unsigned)i * 4096u;
        const int*    mt = mg + i * 64;

#pragma unroll
        for (int kh = 0; kh < 2; ++kh) {
            bf16x8 kf[4];
#pragma unroll
            for (int dc = 0; dc < 4; ++dc)
                kf[dc] = *(const bf16x8*)&kr[(kh * 4 + dc) * 512u + lane * 8u];

            f32x16 s = {0,0,0,0,0,0,0,0,0,0,0,0,0,0,0,0};
            __builtin_amdgcn_s_setprio(1);
#pragma unroll
            for (int dc = 0; dc < 4; ++dc)
                s = __builtin_amdgcn_mfma_f32_32x32x16_bf16(kf[dc], qf[dc], s, 0, 0, 0);
            __builtin_amdgcn_s_setprio(0);

            // mask post-MFMA (r7-proven) from direct int4 global loads
            float p[16];
#pragma unroll
            for (int r1 = 0; r1 < 4; ++r1) {
                int4 mv = *(const int4*)(mt + kh * 32 + r1 * 8 + hi * 4);
                p[r1 * 4 + 0] = exp2_fast(mv.x ? s[r1 * 4 + 0] : -1e30f);
                p[r1 * 4 + 1] = exp2_fast(mv.y ? s[r1 * 4 + 1] : -1e30f);
                p[r1 * 4 + 2] = exp2_fast(mv.z ? s[r1 * 4 + 2] : -1e30f);
                p[r1 * 4 + 3] = exp2_fast(mv.w ? s[r1 * 4 + 3] : -1e30f);
                ls0 += p[r1 * 4 + 0]; ls1 += p[r1 * 4 + 1];
                ls2 += p[r1 * 4 + 2]; ls3 += p[r1 * 4 + 3];
            }

            // pack P -> PV A-frags: cvt_pk + permlane32_swap (r3 algebra,
            // bitwise-identical to the r2 shfl path)
#pragma unroll
            for (int c = 0; c < 2; ++c) {
                unsigned a0 = cvtpk_bf16(p[8 * c + 0], p[8 * c + 1]);
                unsigned a1 = cvtpk_bf16(p[8 * c + 2], p[8 * c + 3]);
                unsigned b0 = cvtpk_bf16(p[8 * c + 4], p[8 * c + 5]);
                unsigned b1 = cvtpk_bf16(p[8 * c + 6], p[8 * c + 7]);
                asm("v_permlane32_swap_b32 %0, %1" : "+v"(a0), "+v"(b0));
                asm("v_permlane32_swap_b32 %0, %1" : "+v"(a1), "+v"(b1));
                union { unsigned w[4]; bf16x8 v; } pa;
                pa.w[0] = a0; pa.w[1] = a1; pa.w[2] = b0; pa.w[3] = b1;
                // V fragments: direct global reads (frag-order, L2-hot);
                // compiler inserts the exact vmcnt before first use
                bf16x8 vf0 = *(const bf16x8*)(vt + ((kh * 2 + c) * 2 + 0) * 512u);
                bf16x8 vf1 = *(const bf16x8*)(vt + ((kh * 2 + c) * 2 + 1) * 512u);
                __builtin_amdgcn_s_setprio(1);
                oacc0 = __builtin_amdgcn_mfma_f32_32x32x16_bf16(pa.v, vf0, oacc0, 0, 0, 0);
                oacc1 = __builtin_amdgcn_mfma_f32_32x32x16_bf16(pa.v, vf1, oacc1, 0, 0, 0);
                __builtin_amdgcn_s_setprio(0);
            }
        }

        // FIFO: tile-i register loads (younger) were waited on above, so
        // K(i+1) is already retired; only K(i+2)'s 2 DMA ops may remain.
        asm volatile("s_waitcnt vmcnt(2)" ::: "memory");
        __builtin_amdgcn_s_barrier();
        cur = (cur == 2u) ? 0u : cur + 1u;
    }
#undef STAGE

    // ---- combine the two key-groups (LDS overlays the dead K buffers) ----
    float lsum = (ls0 + ls1) + (ls2 + ls3);
    lsum += __shfl_xor(lsum, 32);

    __syncthreads();
    if (kgrp == 1) {
#pragma unroll
        for (int r = 0; r < 16; ++r) {
            sm.c.ob[qsub][r][lane]      = oacc0[r];
            sm.c.ob[qsub][16 + r][lane] = oacc1[r];
        }
        sm.c.lsb[qsub][lane] = lsum;
    }
    __syncthreads();
    if (kgrp == 0) {
        lsum += sm.c.lsb[qsub][lane];
#pragma unroll
        for (int r = 0; r < 16; ++r) {
            oacc0[r] += sm.c.ob[qsub][r][lane];
            oacc1[r] += sm.c.ob[qsub][16 + r][lane];
        }
        if (hi == 0) sm.c.rls[qsub][l31] = 1.0f / lsum;
#pragma unroll
        for (int r1 = 0; r1 < 4; ++r1) {
#pragma unroll
            for (int r0 = 0; r0 < 4; ++r0) {
                const int reg = r1 * 4 + r0;
                const unsigned q = r0 + 8u * r1 + 4u * hi;
                const float rr = sm.c.rls[qsub][q];
                float* ob = outp + (((size_t)(b * S_LEN) + q0 + q) * NH + h) * HD + l31;
                ob[0]  = oacc0[reg] * rr;
                ob[32] = oacc1[reg] * rr;
            }
        }
    }
}

extern "C" void kernel_launch(void* const* d_in, const int* in_sizes, int n_in,
                              void* d_out, int out_size, void* d_ws, size_t ws_size,
                              hipStream_t stream) {
    const float* Qp = (const float*)d_in[0];
    const float* Kp = (const float*)d_in[1];
    const float* Vp = (const float*)d_in[2];
    const int* maskp = (const int*)d_in[3];
    float* outp = (float*)d_out;

    ushort* Kws = (ushort*)d_ws;                              // 8.39 MB frag-order K
    ushort* Vws = Kws + (size_t)2 * NH * S_LEN * HD;          // 8.39 MB frag-order V^T

    hipLaunchKernelGGL(prep_k_kernel, dim3(2048), dim3(256), 0, stream, Kp, Kws);
    hipLaunchKernelGGL(prep_v_kernel, dim3(32, 32), dim3(256), 0, stream, Vp, Vws);
    hipLaunchKernelGGL(attn_kernel, dim3(S_LEN / 128, 32), dim3(512), 0, stream,
                       Qp, Kws, Vws, maskp, outp);
}

// Round 10
// 64.158 us; speedup vs baseline: 1.2943x; 1.2943x over previous
//
#include <hip/hip_runtime.h>
#include <hip/hip_bf16.h>

#define S_LEN 2048
#define NH 16
#define HD 64

typedef __attribute__((ext_vector_type(8))) __bf16 bf16x8;
typedef __attribute__((ext_vector_type(16))) float f32x16;

// 0.125 (1/sqrt(64)) * log2(e): folded into Q so softmax uses exp2 directly
#define QSCALE 0.1803368801111204f

static __device__ __forceinline__ ushort f2bf(float f) {
    unsigned int u = __float_as_uint(f);
    u += 0x7fffu + ((u >> 16) & 1u);
    return (ushort)(u >> 16);
}

static __device__ __forceinline__ void gload16(const void* g, void* l) {
    __builtin_amdgcn_global_load_lds(
        (const __attribute__((address_space(1))) unsigned int*)g,
        (__attribute__((address_space(3))) unsigned int*)l, 16, 0, 0);
}
static __device__ __forceinline__ void gload4(const void* g, void* l) {
    __builtin_amdgcn_global_load_lds(
        (const __attribute__((address_space(1))) unsigned int*)g,
        (__attribute__((address_space(3))) unsigned int*)l, 4, 0, 0);
}

static __device__ __forceinline__ unsigned cvtpk_bf16(float lo, float hi) {
    unsigned r;
    asm("v_cvt_pk_bf16_f32 %0, %1, %2" : "=v"(r) : "v"(lo), "v"(hi));
    return r;
}
static __device__ __forceinline__ float exp2_fast(float x) {
    float r;
    asm("v_exp_f32 %0, %1" : "=v"(r) : "v"(x));
    return r;
}

// ---------------------------------------------------------------------------
// K prepass: [B,S,H,D] f32 -> frag-order bf16.  (r2/r7-proven, verbatim)
// ---------------------------------------------------------------------------
__global__ __launch_bounds__(256) void prep_k_kernel(const float* __restrict__ in,
                                                     ushort* __restrict__ out) {
    unsigned t = blockIdx.x * 256u + threadIdx.x;   // 524288 total
    unsigned o = t & 7u;            // d-octet
    unsigned s = (t >> 3) & 2047u;
    unsigned bh = t >> 14;
    unsigned b = bh >> 4, h = bh & 15u;
    const float* src = in + (((size_t)(b * S_LEN) + s) * NH + h) * HD + o * 8;
    float4 x = *(const float4*)src;
    float4 y = *(const float4*)(src + 4);
    union { ushort u[8]; uint4 q; } fu;
    fu.u[0] = f2bf(x.x); fu.u[1] = f2bf(x.y); fu.u[2] = f2bf(x.z); fu.u[3] = f2bf(x.w);
    fu.u[4] = f2bf(y.x); fu.u[5] = f2bf(y.y); fu.u[6] = f2bf(y.z); fu.u[7] = f2bf(y.w);
    unsigned kt = s >> 6, kh = (s >> 5) & 1u, kl = s & 31u;
    unsigned dchunk = o >> 1, ho = o & 1u;
    size_t ci = (((size_t)(bh * 32u + kt) * 2u + kh) * 4u + dchunk) * 64u + kl + 32u * ho;
    *(uint4*)(out + ci * 8u) = fu.q;
}

// ---------------------------------------------------------------------------
// V prepass: [B,S,H,D] f32 -> frag-order V^T bf16.  (r2/r7-proven, verbatim)
// ---------------------------------------------------------------------------
__global__ __launch_bounds__(256) void prep_v_kernel(const float* __restrict__ in,
                                                     ushort* __restrict__ out) {
    __shared__ float T[64][68];
    const unsigned tid = threadIdx.x;
    const unsigned kt = blockIdx.x, bh = blockIdx.y;
    const unsigned b = bh >> 4, h = bh & 15u;
#pragma unroll
    for (int i = 0; i < 4; ++i) {
        unsigned idx = tid + i * 256u;
        unsigned sl = idx >> 4, d4 = (idx & 15u) * 4u;
        float4 v = *(const float4*)(in + (((size_t)(b * S_LEN) + kt * 64u + sl) * NH + h) * HD + d4);
        *(float4*)&T[sl][d4] = v;
    }
    __syncthreads();
#pragma unroll
    for (int it = 0; it < 2; ++it) {
        unsigned ct = tid + it * 256u;
        unsigned l = ct & 63u, sub = ct >> 6;
        unsigned nt = sub & 1u, c = (sub >> 1) & 1u, kh = sub >> 2;
        unsigned d = (l & 31u) + 32u * nt;
        unsigned kb = kh * 32u + c * 16u + (l >> 5) * 8u;
        union { ushort u[8]; uint4 q; } fu;
#pragma unroll
        for (int j = 0; j < 8; ++j) fu.u[j] = f2bf(T[kb + j][d]);
        *(uint4*)(out + ((size_t)(bh * 32u + kt) * 8u + sub) * 512u + l * 8u) = fu.q;
    }
}

// ---------------------------------------------------------------------------
// Flash attention: 8 waves (4 q-subtiles x 2 key-groups), KV tile 64,
// swapped QK^T, POST-MFMA cndmask masking (C-init BANNED), permlane32_swap
// P-pack (r9-proven correct; removes 16 ds_bpermute/tile from LDS pipe),
// frag-order K+V LDS via global_load_lds (r8-proven), double-buffered,
// vmcnt(0) drain per tile (counted-vmcnt with mixed VMEM streams is BANNED
// per r9: register global loads share the counter and get drained).
// ---------------------------------------------------------------------------
struct TileMem {
    ushort K[2][2][4096];   // [kgrp][pb] 32 KB
    ushort V[2][2][4096];   // 32 KB
    int    mb[2][2][64];    // 2 KB (int mask)
};
struct CombMem {
    float ob[4][32][64];    // 32 KB
    float lsb[4][64];
    float rls[4][32];
};
union SMemU { TileMem s; CombMem c; };

__global__ __launch_bounds__(512, 4) void attn_kernel(const float* __restrict__ Qp,
                                                      const ushort* __restrict__ Kws,
                                                      const ushort* __restrict__ Vws,
                                                      const int* __restrict__ maskp,
                                                      float* __restrict__ outp) {
    __shared__ __align__(16) SMemU sm;

    const unsigned tid = threadIdx.x;
    const unsigned wid = tid >> 6;
    const unsigned lane = tid & 63u;
    const unsigned l31 = lane & 31u;
    const unsigned hi = lane >> 5;
    const unsigned qsub = wid & 3u;
    const unsigned kgrp = wid >> 2;

    const unsigned bh = blockIdx.y;
    const unsigned b = bh >> 4, h = bh & 15u;
    const unsigned q0 = blockIdx.x * 128u + qsub * 32u;

    // Q fragments (B-operand of swapped QK^T): lane holds Q[q0+l31][16dc+8hi+j]
    bf16x8 qf[4];
    {
        const float* qb = Qp + (((size_t)(b * S_LEN) + q0 + l31) * NH + h) * HD + hi * 8u;
#pragma unroll
        for (int dc = 0; dc < 4; ++dc) {
            float4 x = *(const float4*)(qb + dc * 16);
            float4 y = *(const float4*)(qb + dc * 16 + 4);
            union { ushort u[8]; bf16x8 v; } fu;
            fu.u[0] = f2bf(x.x * QSCALE); fu.u[1] = f2bf(x.y * QSCALE);
            fu.u[2] = f2bf(x.z * QSCALE); fu.u[3] = f2bf(x.w * QSCALE);
            fu.u[4] = f2bf(y.x * QSCALE); fu.u[5] = f2bf(y.y * QSCALE);
            fu.u[6] = f2bf(y.z * QSCALE); fu.u[7] = f2bf(y.w * QSCALE);
            qf[dc] = fu.v;
        }
    }

    f32x16 oacc0 = {0,0,0,0,0,0,0,0,0,0,0,0,0,0,0,0};
    f32x16 oacc1 = {0,0,0,0,0,0,0,0,0,0,0,0,0,0,0,0};
    float ls0 = 0.f, ls1 = 0.f, ls2 = 0.f, ls3 = 0.f;

    // global staging pointers (per-lane), group kgrp covers tiles kgrp*16..+15
    const char* kgp = (const char*)Kws + (size_t)bh * 262144u
                    + ((size_t)kgrp * 131072u) + (2u * qsub) * 1024u + lane * 16u;
    const char* vgp = (const char*)Vws + (size_t)bh * 262144u
                    + ((size_t)kgrp * 131072u) + (2u * qsub) * 1024u + lane * 16u;
    const int* mgp = maskp + (size_t)b * S_LEN + kgrp * 1024u + lane;

    ushort* klb = &sm.s.K[kgrp][0][2u * qsub * 512u];
    ushort* vlb = &sm.s.V[kgrp][0][2u * qsub * 512u];
    int*    mlb = &sm.s.mb[kgrp][0][0];
    const ushort* krd = &sm.s.K[kgrp][0][0];
    const ushort* vrd = &sm.s.V[kgrp][0][0];

#define STAGE(I, PB) do {                                                      \
    const size_t toff = (size_t)(I) * 8192u;                                   \
    gload16(kgp + toff,          klb + (PB) * 4096u);                          \
    gload16(kgp + toff + 1024u,  klb + (PB) * 4096u + 512u);                   \
    gload16(vgp + toff,          vlb + (PB) * 4096u);                          \
    gload16(vgp + toff + 1024u,  vlb + (PB) * 4096u + 512u);                   \
    if (qsub == 0) gload4(mgp + (I) * 64, mlb + (PB) * 64u);                   \
  } while (0)

    STAGE(0, 0u);
    asm volatile("s_waitcnt vmcnt(0)" ::: "memory");
    __syncthreads();

    unsigned pb = 0;
    for (int i = 0; i < 16; ++i) {
        if (i < 15) STAGE(i + 1, pb ^ 1u);
        const ushort* kr = krd + pb * 4096u;
        const ushort* vr = vrd + pb * 4096u;
        const int*    mr = mlb + pb * 64u;

#pragma unroll
        for (int kh = 0; kh < 2; ++kh) {
            bf16x8 kf[4];
#pragma unroll
            for (int dc = 0; dc < 4; ++dc)
                kf[dc] = *(const bf16x8*)&kr[(kh * 4 + dc) * 512u + lane * 8u];

            f32x16 s = {0,0,0,0,0,0,0,0,0,0,0,0,0,0,0,0};
            __builtin_amdgcn_s_setprio(1);
#pragma unroll
            for (int dc = 0; dc < 4; ++dc)
                s = __builtin_amdgcn_mfma_f32_32x32x16_bf16(kf[dc], qf[dc], s, 0, 0, 0);
            __builtin_amdgcn_s_setprio(0);

            // mask post-MFMA (r7-proven): masked keys -> exp2(-1e30) = 0
            float p[16];
#pragma unroll
            for (int r1 = 0; r1 < 4; ++r1) {
                int mv[4];
                *(int4*)mv = *(const int4*)&mr[kh * 32 + r1 * 8 + hi * 4];
#pragma unroll
                for (int r0 = 0; r0 < 4; ++r0) {
                    const int reg = r1 * 4 + r0;
                    float t = mv[r0] ? s[reg] : -1e30f;
                    p[reg] = exp2_fast(t);
                }
                ls0 += p[r1 * 4 + 0]; ls1 += p[r1 * 4 + 1];
                ls2 += p[r1 * 4 + 2]; ls3 += p[r1 * 4 + 3];
            }

            // pack P -> PV A-frags: cvt_pk + permlane32_swap (r9-proven)
#pragma unroll
            for (int c = 0; c < 2; ++c) {
                unsigned a0 = cvtpk_bf16(p[8 * c + 0], p[8 * c + 1]);
                unsigned a1 = cvtpk_bf16(p[8 * c + 2], p[8 * c + 3]);
                unsigned b0 = cvtpk_bf16(p[8 * c + 4], p[8 * c + 5]);
                unsigned b1 = cvtpk_bf16(p[8 * c + 6], p[8 * c + 7]);
                asm("v_permlane32_swap_b32 %0, %1" : "+v"(a0), "+v"(b0));
                asm("v_permlane32_swap_b32 %0, %1" : "+v"(a1), "+v"(b1));
                union { unsigned w[4]; bf16x8 v; } pa;
                pa.w[0] = a0; pa.w[1] = a1; pa.w[2] = b0; pa.w[3] = b1;
                bf16x8 vf0 = *(const bf16x8*)&vr[((kh * 2 + c) * 2 + 0) * 512u + lane * 8u];
                bf16x8 vf1 = *(const bf16x8*)&vr[((kh * 2 + c) * 2 + 1) * 512u + lane * 8u];
                __builtin_amdgcn_s_setprio(1);
                oacc0 = __builtin_amdgcn_mfma_f32_32x32x16_bf16(pa.v, vf0, oacc0, 0, 0, 0);
                oacc1 = __builtin_amdgcn_mfma_f32_32x32x16_bf16(pa.v, vf1, oacc1, 0, 0, 0);
                __builtin_amdgcn_s_setprio(0);
            }
        }
        asm volatile("s_waitcnt vmcnt(0)" ::: "memory");
        __syncthreads();
        pb ^= 1u;
    }
#undef STAGE

    // ---- combine the two key-groups (LDS overlays the dead tile buffers) ----
    float lsum = (ls0 + ls1) + (ls2 + ls3);
    lsum += __shfl_xor(lsum, 32);

    if (kgrp == 1) {
#pragma unroll
        for (int r = 0; r < 16; ++r) {
            sm.c.ob[qsub][r][lane]      = oacc0[r];
            sm.c.ob[qsub][16 + r][lane] = oacc1[r];
        }
        sm.c.lsb[qsub][lane] = lsum;
    }
    __syncthreads();
    if (kgrp == 0) {
        lsum += sm.c.lsb[qsub][lane];
#pragma unroll
        for (int r = 0; r < 16; ++r) {
            oacc0[r] += sm.c.ob[qsub][r][lane];
            oacc1[r] += sm.c.ob[qsub][16 + r][lane];
        }
        if (hi == 0) sm.c.rls[qsub][l31] = 1.0f / lsum;
#pragma unroll
        for (int r1 = 0; r1 < 4; ++r1) {
#pragma unroll
            for (int r0 = 0; r0 < 4; ++r0) {
                const int reg = r1 * 4 + r0;
                const unsigned q = r0 + 8u * r1 + 4u * hi;
                const float rr = sm.c.rls[qsub][q];
                float* ob = outp + (((size_t)(b * S_LEN) + q0 + q) * NH + h) * HD + l31;
                ob[0]  = oacc0[reg] * rr;
                ob[32] = oacc1[reg] * rr;
            }
        }
    }
}

extern "C" void kernel_launch(void* const* d_in, const int* in_sizes, int n_in,
                              void* d_out, int out_size, void* d_ws, size_t ws_size,
                              hipStream_t stream) {
    const float* Qp = (const float*)d_in[0];
    const float* Kp = (const float*)d_in[1];
    const float* Vp = (const float*)d_in[2];
    const int* maskp = (const int*)d_in[3];
    float* outp = (float*)d_out;

    ushort* Kws = (ushort*)d_ws;                              // 8.39 MB frag-order K
    ushort* Vws = Kws + (size_t)2 * NH * S_LEN * HD;          // 8.39 MB frag-order V^T

    hipLaunchKernelGGL(prep_k_kernel, dim3(2048), dim3(256), 0, stream, Kp, Kws);
    hipLaunchKernelGGL(prep_v_kernel, dim3(32, 32), dim3(256), 0, stream, Vp, Vws);
    hipLaunchKernelGGL(attn_kernel, dim3(S_LEN / 128, 32), dim3(512), 0, stream,
                       Qp, Kws, Vws, maskp, outp);
}